// Round 7
// baseline (478.463 us; speedup 1.0000x reference)
//
#include <hip/hip_runtime.h>

constexpr int N = 50000;
constexpr int E = 800000;
constexpr int D = 128;
constexpr int MASKN = 25000;
constexpr int CAP = 96; // bucket capacity; deg ~ Poisson(16), P(>96) ~ 0

typedef _Float16 half8 __attribute__((ext_vector_type(8)));
typedef _Float16 half4 __attribute__((ext_vector_type(4)));

#define DOT_STEP(w, a, acc)                                                    \
    acc = fmaf(w.x, a.x, acc);                                                 \
    acc = fmaf(w.y, a.y, acc);                                                 \
    acc = fmaf(w.z, a.z, acc);                                                 \
    acc = fmaf(w.w, a.w, acc)

#define ROW8(X) X(0) X(1) X(2) X(3) X(4) X(5) X(6) X(7)
#define ROW16(X) X(0) X(1) X(2) X(3) X(4) X(5) X(6) X(7)                       \
                 X(8) X(9) X(10) X(11) X(12) X(13) X(14) X(15)

// ---------------- one-pass bucket-CSR build (uint16 col) ----------------
// cnt_src: out-degree histogram. cursor: in-degree histogram AND bucket cursor.
// col entries are 2B; a deg~16 row's bucket spans 32B -> scattered stores to
// one row mostly share a 64B line (write-amp cut vs 4B entries).

__global__ void k_build(const int* __restrict__ src, const int* __restrict__ dst,
                        int* __restrict__ cnt_src, int* __restrict__ cursor,
                        unsigned short* __restrict__ col) {
    int e = blockIdx.x * blockDim.x + threadIdx.x;
    if (e < E) {
        int s = src[e], d = dst[e];
        atomicAdd(&cnt_src[s], 1);
        int p = atomicAdd(&cursor[d], 1);
        col[(size_t)d * CAP + p] = (unsigned short)s;
    }
}

// ---------------- fused setup: 4x W-transpose + dinv + mflag ----------------

__global__ void k_misc(const float4* __restrict__ W1, const float4* __restrict__ W2,
                       const float4* __restrict__ WE, const float4* __restrict__ WD,
                       float4* __restrict__ Wr1, float4* __restrict__ Wr2,
                       float4* __restrict__ WrE, float4* __restrict__ WrD,
                       const int* __restrict__ cs, const int* __restrict__ cd,
                       float* __restrict__ dinv_out, float* __restrict__ dinv_in,
                       const int* __restrict__ mask_nodes, int* __restrict__ mflag) {
    int b = blockIdx.x;
    if (b < 64) { // Wr[k4*128+o] = W[o*32+k4], 4 matrices x 16 blocks
        int m = b >> 4;
        int idx = (b & 15) * 256 + threadIdx.x;
        const float4* W = m == 0 ? W1 : m == 1 ? W2 : m == 2 ? WE : WD;
        float4* Wr = m == 0 ? Wr1 : m == 1 ? Wr2 : m == 2 ? WrE : WrD;
        int o = idx >> 5, k4 = idx & 31;
        Wr[k4 * 128 + o] = W[idx];
    } else if (b < 64 + 196) {
        int i = (b - 64) * 256 + threadIdx.x;
        if (i < N) {
            int a = cs[i] > 1 ? cs[i] : 1;
            int bb = cd[i] > 1 ? cd[i] : 1;
            dinv_out[i] = rsqrtf((float)a);
            dinv_in[i] = rsqrtf((float)bb);
        }
    } else {
        int i = (b - 260) * 256 + threadIdx.x;
        if (i < MASKN) mflag[mask_nodes[i]] = 1;
    }
}

// ---------------- feature prep: masked x scaled by deg_out^-0.5, fp16 out ----

__global__ void k_prep(const float4* __restrict__ x, const float4* __restrict__ tok,
                       const int* __restrict__ mflag, const float* __restrict__ dinv_out,
                       half4* __restrict__ Ah4) {
    int i = blockIdx.x * blockDim.x + threadIdx.x; // over N*32 float4s
    if (i < N * 32) {
        int row = i >> 5;
        int c = i & 31;
        float s = dinv_out[row];
        float4 v = mflag[row] ? tok[c] : x[i];
        half4 h;
        h[0] = (_Float16)(v.x * s);
        h[1] = (_Float16)(v.y * s);
        h[2] = (_Float16)(v.z * s);
        h[3] = (_Float16)(v.w * s);
        Ah4[i] = h;
    }
}

// ---------------- SpMM: B[row] = sum over bucket neighbors of Ah[col] ----------
// 256 thr = 4 waves, one row/wave; quarter-wave (16 lanes x 16B) per edge:
// 4 edges per vector instruction, 2 gathers in flight, f32 accumulate.

__launch_bounds__(256)
__global__ void k_spmm(const half8* __restrict__ Ah8, float4* __restrict__ B4,
                       const int* __restrict__ deg, const unsigned short* __restrict__ col,
                       const int* __restrict__ rows, int nrows) {
    int wv = threadIdx.x >> 6, lane = threadIdx.x & 63;
    int q = lane >> 4, j = lane & 15;
    int rr = blockIdx.x * 4 + wv;
    if (rr >= nrows) return;
    int row = rows ? rows[rr] : rr;
    int dg = deg[row];
    const unsigned short* crow = col + (size_t)row * CAP;
    float a0 = 0.f, a1 = 0.f, a2 = 0.f, a3 = 0.f;
    float a4 = 0.f, a5 = 0.f, a6 = 0.f, a7 = 0.f;
    int e = q;
    for (; e + 4 < dg; e += 8) {
        int c0 = crow[e], c1 = crow[e + 4];
        half8 h0 = Ah8[(size_t)c0 * 16 + j];
        half8 h1 = Ah8[(size_t)c1 * 16 + j];
#define SP_ACC(i) a##i += (float)h0[i]; a##i += (float)h1[i];
        ROW8(SP_ACC)
#undef SP_ACC
    }
    if (e < dg) {
        int c0 = crow[e];
        half8 h0 = Ah8[(size_t)c0 * 16 + j];
#define SP_ACC1(i) a##i += (float)h0[i];
        ROW8(SP_ACC1)
#undef SP_ACC1
    }
#pragma unroll
    for (int o = 16; o <= 32; o <<= 1) {
#define SP_SHFL(i) a##i += __shfl_xor(a##i, o);
        ROW8(SP_SHFL)
#undef SP_SHFL
    }
    if (q == 0) {
        B4[(size_t)row * 32 + j * 2] = make_float4(a0, a1, a2, a3);
        B4[(size_t)row * 32 + j * 2 + 1] = make_float4(a4, a5, a6, a7);
    }
}

// ---------------- dense: thread t = output col, 16 rows/block, coalesced Wr ----

template <bool LN, bool SCALE_OUT, bool MASK_ZERO, bool OUT_HALF>
__launch_bounds__(128)
__global__ void k_dense(const float* __restrict__ in, float* __restrict__ out,
                        _Float16* __restrict__ outh,
                        const float4* __restrict__ Wr4, const float* __restrict__ bias,
                        const float* __restrict__ g, const float* __restrict__ be,
                        const float* __restrict__ aP, const float* __restrict__ dinv_in,
                        const float* __restrict__ dinv_out, const int* __restrict__ mflag) {
    __shared__ float sh[16 * 128];
    __shared__ float red[64];
    int t = threadIdx.x;
    int r0 = blockIdx.x * 16; // N % 16 == 0
    {
        const float4* inb = (const float4*)(in + (size_t)r0 * 128);
        float4* s4 = (float4*)sh;
#pragma unroll
        for (int jj = 0; jj < 4; ++jj) s4[t + 128 * jj] = inb[t + 128 * jj];
    }
    __syncthreads();
    const float4* sh4 = (const float4*)sh;
#define ACC_DECL(i) float acc##i = 0.f;
    ROW16(ACC_DECL)
#undef ACC_DECL
#pragma unroll 2
    for (int k4 = 0; k4 < 32; ++k4) {
        float4 w = Wr4[k4 * 128 + t];
#define DENSE_FMA(i)                                                           \
        {                                                                      \
            float4 a = sh4[i * 32 + k4];                                       \
            DOT_STEP(w, a, acc##i);                                            \
        }
        ROW16(DENSE_FMA)
#undef DENSE_FMA
    }
#define V_DECL(i) float v##i = acc##i;
    ROW16(V_DECL)
#undef V_DECL
    if constexpr (LN) {
        float bt = bias[t];
#define LN_PRE(i) v##i = (v##i + bt) * dinv_in[r0 + i];
        ROW16(LN_PRE)
#undef LN_PRE
#define LN_DECL(i) float s##i = v##i, q##i = v##i * v##i;
        ROW16(LN_DECL)
#undef LN_DECL
#pragma unroll
        for (int o = 32; o > 0; o >>= 1) {
#define LN_SHFL(i)                                                             \
            s##i += __shfl_xor(s##i, o);                                       \
            q##i += __shfl_xor(q##i, o);
            ROW16(LN_SHFL)
#undef LN_SHFL
        }
        if ((t & 63) == 0) {
            int wv = t >> 6;
#define LN_RED(i)                                                              \
            red[wv * 32 + 2 * i] = s##i;                                       \
            red[wv * 32 + 2 * i + 1] = q##i;
            ROW16(LN_RED)
#undef LN_RED
        }
        __syncthreads();
        float gt = g[t], bet = be[t], alpha = aP[0];
#define LN_ROW(i)                                                              \
        {                                                                      \
            float S = red[2 * i] + red[32 + 2 * i];                            \
            float Q = red[2 * i + 1] + red[32 + 2 * i + 1];                    \
            float mu = S * (1.f / D);                                          \
            float var = Q * (1.f / D) - mu * mu;                               \
            float rs = rsqrtf(var + 1e-5f);                                    \
            v##i = (v##i - mu) * rs * gt + bet;                                \
            v##i = v##i >= 0.f ? v##i : alpha * v##i;                          \
        }
        ROW16(LN_ROW)
#undef LN_ROW
    }
    if constexpr (MASK_ZERO) {
#define MZ(i) if (mflag[r0 + i]) v##i = 0.f;
        ROW16(MZ)
#undef MZ
    }
    if constexpr (SCALE_OUT) {
#define SO(i) v##i *= dinv_out[r0 + i];
        ROW16(SO)
#undef SO
    }
    if constexpr (OUT_HALF) {
#define STOREH(i) outh[(size_t)(r0 + i) * 128 + t] = (_Float16)v##i;
        ROW16(STOREH)
#undef STOREH
    } else {
#define STORE(i) out[(size_t)(r0 + i) * 128 + t] = v##i;
        ROW16(STORE)
#undef STORE
    }
}

// decoder fc + degnorm + SCE loss over masked rows (8 rows/block)
__launch_bounds__(128)
__global__ void k_loss(const float* __restrict__ agg, const float* __restrict__ x,
                       const float4* __restrict__ Wr4, const float* __restrict__ bd,
                       const float* __restrict__ dinv_in, const int* __restrict__ mask_nodes,
                       float* __restrict__ outp) {
    __shared__ float sh[8 * 128];
    __shared__ float red[48];
    __shared__ int shm[8];
    int t = threadIdx.x;
    int i0 = blockIdx.x * 8; // MASKN % 8 == 0
    if (t < 8) shm[t] = mask_nodes[i0 + t];
    __syncthreads();
#pragma unroll
    for (int i = 0; i < 8; ++i) sh[i * 128 + t] = agg[(size_t)shm[i] * 128 + t];
    __syncthreads();
    const float4* sh4 = (const float4*)sh;
    float acc0 = 0.f, acc1 = 0.f, acc2 = 0.f, acc3 = 0.f;
    float acc4 = 0.f, acc5 = 0.f, acc6 = 0.f, acc7 = 0.f;
#pragma unroll 2
    for (int k4 = 0; k4 < 32; ++k4) {
        float4 w = Wr4[k4 * 128 + t];
#define LOSS_FMA(i)                                                            \
        {                                                                      \
            float4 a = sh4[i * 32 + k4];                                       \
            DOT_STEP(w, a, acc##i);                                            \
        }
        ROW8(LOSS_FMA)
#undef LOSS_FMA
    }
    float bt = bd[t];
#define LOSS_RXC(i)                                                            \
    float r##i = (acc##i + bt) * dinv_in[shm[i]];                              \
    float xv##i = x[(size_t)shm[i] * 128 + t];                                 \
    float a##i = r##i * r##i, b##i = xv##i * xv##i, c##i = r##i * xv##i;
    ROW8(LOSS_RXC)
#undef LOSS_RXC
#pragma unroll
    for (int o = 32; o > 0; o >>= 1) {
#define LOSS_SHFL(i)                                                           \
        a##i += __shfl_xor(a##i, o);                                           \
        b##i += __shfl_xor(b##i, o);                                           \
        c##i += __shfl_xor(c##i, o);
        ROW8(LOSS_SHFL)
#undef LOSS_SHFL
    }
    if ((t & 63) == 0) {
        int wv = t >> 6;
#define LOSS_RED(i)                                                            \
        red[wv * 24 + 3 * i] = a##i;                                           \
        red[wv * 24 + 3 * i + 1] = b##i;                                       \
        red[wv * 24 + 3 * i + 2] = c##i;
        ROW8(LOSS_RED)
#undef LOSS_RED
    }
    __syncthreads();
    if (t == 0) {
        float sum = 0.f;
#pragma unroll
        for (int i = 0; i < 8; ++i) {
            float A_ = red[3 * i] + red[24 + 3 * i];
            float B_ = red[3 * i + 1] + red[24 + 3 * i + 1];
            float C_ = red[3 * i + 2] + red[24 + 3 * i + 2];
            float nr = fmaxf(sqrtf(A_), 1e-12f);
            float nx = fmaxf(sqrtf(B_), 1e-12f);
            float term = 1.f - C_ / (nr * nx);
            sum += term * term;
        }
        atomicAdd(outp, sum * (1.f / MASKN));
    }
}

// ---------------- launch ----------------

extern "C" void kernel_launch(void* const* d_in, const int* in_sizes, int n_in,
                              void* d_out, int out_size, void* d_ws, size_t ws_size,
                              hipStream_t stream) {
    const float* x = (const float*)d_in[0];
    const float* tok = (const float*)d_in[1];
    const float* W1 = (const float*)d_in[2];
    const float* b1 = (const float*)d_in[3];
    const float* g1 = (const float*)d_in[4];
    const float* be1 = (const float*)d_in[5];
    const float* a1 = (const float*)d_in[6];
    const float* W2 = (const float*)d_in[7];
    const float* b2 = (const float*)d_in[8];
    const float* g2 = (const float*)d_in[9];
    const float* be2 = (const float*)d_in[10];
    const float* a2 = (const float*)d_in[11];
    const float* We2d = (const float*)d_in[12];
    const float* Wd = (const float*)d_in[13];
    const float* bd = (const float*)d_in[14];
    const int* src = (const int*)d_in[15];
    const int* dst = (const int*)d_in[16];
    const int* mask_nodes = (const int*)d_in[17];

    char* w = (char*)d_ws;
    _Float16* Ah = (_Float16*)w;        w += (size_t)N * D * 2;
    float* Bf = (float*)w;              w += (size_t)N * D * 4;
    float* Hf = (float*)w;              w += (size_t)N * D * 4;
    unsigned short* col = (unsigned short*)w; w += (size_t)N * CAP * 2;
    int* cnt_src = (int*)w;             w += (size_t)N * 4;
    int* cursor = (int*)w;              w += (size_t)N * 4; // becomes deg_in
    int* mflag = (int*)w;               w += (size_t)N * 4;
    float* dinv_out = (float*)w;        w += (size_t)N * 4;
    float* dinv_in = (float*)w;         w += (size_t)N * 4;
    float* Wr1 = (float*)w;             w += (size_t)D * D * 4;
    float* Wr2 = (float*)w;             w += (size_t)D * D * 4;
    float* WrE = (float*)w;             w += (size_t)D * D * 4;
    float* WrD = (float*)w;             w += (size_t)D * D * 4;

    // zero cnt_src, cursor, mflag (contiguous 3*N ints) + output scalar
    hipMemsetAsync(cnt_src, 0, (size_t)3 * N * 4, stream);
    hipMemsetAsync(d_out, 0, sizeof(float), stream);

    k_build<<<(E + 255) / 256, 256, 0, stream>>>(src, dst, cnt_src, cursor, col);
    k_misc<<<358, 256, 0, stream>>>(
        (const float4*)W1, (const float4*)W2, (const float4*)We2d, (const float4*)Wd,
        (float4*)Wr1, (float4*)Wr2, (float4*)WrE, (float4*)WrD,
        cnt_src, cursor, dinv_out, dinv_in, mask_nodes, mflag);
    k_prep<<<(N * 32 + 255) / 256, 256, 0, stream>>>((const float4*)x, (const float4*)tok,
                                                     mflag, dinv_out, (half4*)Ah);
    int ndense = N / 16;    // 3125
    int nloss = MASKN / 8;  // 3125
    int nspmm = (N + 3) / 4;
    // conv1: agg (fp16 gather)
    k_spmm<<<nspmm, 256, 0, stream>>>((const half8*)Ah, (float4*)Bf, cursor, col, nullptr, N);
    // conv1 epilogue -> fp16, pre-scaled by deg_out^-0.5
    k_dense<true, true, false, true><<<ndense, 128, 0, stream>>>(
        Bf, nullptr, Ah, (const float4*)Wr1, b1, g1, be1, a1, dinv_in, dinv_out, nullptr);
    // conv2: agg
    k_spmm<<<nspmm, 256, 0, stream>>>((const half8*)Ah, (float4*)Bf, cursor, col, nullptr, N);
    // conv2 epilogue: h2 (f32)
    k_dense<true, false, false, false><<<ndense, 128, 0, stream>>>(
        Bf, Hf, nullptr, (const float4*)Wr2, b2, g2, be2, a2, dinv_in, dinv_out, nullptr);
    // encoder_to_decoder + re-mask + pre-scale -> fp16
    k_dense<false, true, true, true><<<ndense, 128, 0, stream>>>(
        Hf, nullptr, Ah, (const float4*)WrE, nullptr, nullptr, nullptr, nullptr,
        dinv_in, dinv_out, mflag);
    // conv3: agg, masked rows only
    k_spmm<<<(MASKN + 3) / 4, 256, 0, stream>>>((const half8*)Ah, (float4*)Bf, cursor, col,
                                                mask_nodes, MASKN);
    // decoder fc + SCE loss
    k_loss<<<nloss, 128, 0, stream>>>(Bf, x, (const float4*)WrD, bd,
                                      dinv_in, mask_nodes, (float*)d_out);
}